// Round 4
// baseline (518.264 us; speedup 1.0000x reference)
//
#include <hip/hip_runtime.h>

// ---------------------------------------------------------------------------
// TreeCaps forward, MI355X fp32 implementation.
// Fixed forest: per graph of 1024 nodes, node p's children are 4p+1..4p+4;
// nodes 0..255 are internal (updated each layer), 256..1023 are leaves.
// R2: k_dsweep 1 block per node -> WT read exactly once.
// R3: conv fusion at 1 block/CU -> regression (staging serialized).
// R4: occupancy attack -> WIN (523->476): conv 16-row/512-block (2/CU),
//     VTS 64-row/512-block, gamma fused into dsweep, topk+buildU fused.
// R5: conv gather-fusion retry at R4 tiling + K-loop dbuf -> NEUTRAL (477).
//     Conv phase is covered; kept (fewer dispatches, less traffic).
// R6: (this round) VTS barrier elimination + zsweep occupancy:
//   - vtsA/vtsB remapped: p = tid&15 (j-chunk), row = tid>>4 -> a row's 16
//     partials sit in 16 adjacent lanes of ONE wave; reduction = 4 shfl_xor
//     (masks 8,4,2,1) = EXACT same pairing as the old stride-512..64 LDS
//     tree -> bit-identical sums, ~10-12 barriers -> 1 per kernel.
//   - Vsum/U/ms staged chunk-transposed with stride-17 pad (conflict-free
//     16-consecutive-float4 reads; bijective 17-stride writes).
//   - zsweep: 32 n-chunks of 32 (grid 1600, 25 waves/CU; R4 precedent).
// ---------------------------------------------------------------------------

#define BG      32
#define NPG     1024
#define HH      128
#define NLAY    4
#define INT_PG  256
#define M_INT   8192      // BG*INT_PG
#define NN      32768     // BG*NPG
#define EPG     1023
#define DCC     16
#define NS      50

// ------- embedding: h0 = concat(type_emb[t], token_emb[k]); leaves to both -
__global__ void k_embed(const int* __restrict__ tids, const int* __restrict__ kids,
                        const float* __restrict__ temb, const float* __restrict__ kemb,
                        float* __restrict__ hA, float* __restrict__ hB) {
  int idx = blockIdx.x * 256 + threadIdx.x;        // NN*32
  int n = idx >> 5, c4 = idx & 31;
  float4 v;
  if (c4 < 16) v = *(const float4*)(temb + tids[n] * 64 + c4 * 4);
  else         v = *(const float4*)(kemb + kids[n] * 64 + (c4 - 16) * 4);
  *(float4*)(hA + n * 128 + c4 * 4) = v;
  if ((n & 1023) >= INT_PG)                        // leaves constant in both bufs
    *(float4*)(hB + n * 128 + c4 * 4) = v;
}

// --- fused gather+conv: new_h = relu(hl@Wl + hr@Wr + h@Wt + b) -------------
// [8192 rows, K=384, N=128]; block = 256 thr, 16 rows x 128 cols, 2x4/thread.
// 512 blocks (2/CU). Children of the block's 16 parents = contiguous local
// slice staged to LDS with k_gather's exact fma order. K-loop double-buffered.
__global__ __launch_bounds__(256) void k_conv(
    const float* __restrict__ hp, float* __restrict__ hn,
    const int* __restrict__ src, const float* __restrict__ lw,
    const float* __restrict__ rw,
    const float* __restrict__ Wl, const float* __restrict__ Wr,
    const float* __restrict__ Wt, const float* __restrict__ bias,
    float* __restrict__ feat) {
  __shared__ float Ws[2][32][128];   // 32 KB
  __shared__ float AsT[2][32][20];   // 5 KB, padded
  __shared__ float hlS[16][128];     // 8 KB
  __shared__ float hrS[16][128];     // 8 KB
  int tid = threadIdx.x;
  int tx = tid & 31, ty = tid >> 5;          // ty 0..7 -> rows 2*ty, 2*ty+1
  int rowBase = blockIdx.x * 16;
  int g = rowBase >> 8, plBase = rowBase & 255;
  int nodeBase = g * NPG + plBase;

  // ---- stage weighted child sums for 16 parents (k_gather fma order) ----
  #pragma unroll
  for (int t = 0; t < 2; ++t) {
    int it = t * 256 + tid;                  // 0..511
    int pw = it >> 5, c4 = it & 31;
    int pl = plBase + pw;
    float4 al = make_float4(0.f, 0.f, 0.f, 0.f);
    float4 ar = make_float4(0.f, 0.f, 0.f, 0.f);
    #pragma unroll
    for (int j = 0; j < 4; ++j) {
      int cc = 4 * pl + 1 + j;
      if (cc < NPG) {
        int e = g * EPG + cc - 1;
        int child = src[e];
        float lv = lw[e], rv = rw[e];
        float4 hv = *(const float4*)(hp + child * 128 + c4 * 4);
        al.x = fmaf(lv, hv.x, al.x); al.y = fmaf(lv, hv.y, al.y);
        al.z = fmaf(lv, hv.z, al.z); al.w = fmaf(lv, hv.w, al.w);
        ar.x = fmaf(rv, hv.x, ar.x); ar.y = fmaf(rv, hv.y, ar.y);
        ar.z = fmaf(rv, hv.z, ar.z); ar.w = fmaf(rv, hv.w, ar.w);
      }
    }
    *(float4*)&hlS[pw][c4 * 4] = al;
    *(float4*)&hrS[pw][c4 * 4] = ar;
  }
  __syncthreads();

  float acc[2][4] = {};
  int sr = tid >> 3, sc4 = (tid & 7) * 4;    // valid for tid<128: sr 0..15

  // prologue: load kc=0 into buffer 0 (ssel=0 -> hlS)
  {
    float4 av = make_float4(0.f, 0.f, 0.f, 0.f);
    if (tid < 128) av = *(const float4*)&hlS[sr][sc4];
    const float* wsrc = Wl;                  // kcol = 0
    int f0 = tid, f1 = tid + 256, f2 = tid + 512, f3 = tid + 768;
    float4 wv0 = *(const float4*)(wsrc + (f0 >> 5) * 128 + (f0 & 31) * 4);
    float4 wv1 = *(const float4*)(wsrc + (f1 >> 5) * 128 + (f1 & 31) * 4);
    float4 wv2 = *(const float4*)(wsrc + (f2 >> 5) * 128 + (f2 & 31) * 4);
    float4 wv3 = *(const float4*)(wsrc + (f3 >> 5) * 128 + (f3 & 31) * 4);
    if (tid < 128) {
      AsT[0][sc4 + 0][sr] = av.x; AsT[0][sc4 + 1][sr] = av.y;
      AsT[0][sc4 + 2][sr] = av.z; AsT[0][sc4 + 3][sr] = av.w;
    }
    *(float4*)&Ws[0][f0 >> 5][(f0 & 31) * 4] = wv0;
    *(float4*)&Ws[0][f1 >> 5][(f1 & 31) * 4] = wv1;
    *(float4*)&Ws[0][f2 >> 5][(f2 & 31) * 4] = wv2;
    *(float4*)&Ws[0][f3 >> 5][(f3 & 31) * 4] = wv3;
  }
  __syncthreads();

  for (int kc = 0; kc < 12; ++kc) {
    int cur = kc & 1, nxt = cur ^ 1;
    if (kc < 11) {                           // prefetch kc+1 into nxt
      int kc1 = kc + 1;
      int ssel = kc1 >> 2, kcol = (kc1 & 3) * 32;
      float4 av = make_float4(0.f, 0.f, 0.f, 0.f);
      if (tid < 128) {
        if (ssel == 0)      av = *(const float4*)&hlS[sr][kcol + sc4];
        else if (ssel == 1) av = *(const float4*)&hrS[sr][kcol + sc4];
        else                av = *(const float4*)(hp + (nodeBase + sr) * 128 + kcol + sc4);
      }
      const float* wsrc = ((ssel == 0) ? Wl : (ssel == 1) ? Wr : Wt) + kcol * 128;
      int f0 = tid, f1 = tid + 256, f2 = tid + 512, f3 = tid + 768;
      float4 wv0 = *(const float4*)(wsrc + (f0 >> 5) * 128 + (f0 & 31) * 4);
      float4 wv1 = *(const float4*)(wsrc + (f1 >> 5) * 128 + (f1 & 31) * 4);
      float4 wv2 = *(const float4*)(wsrc + (f2 >> 5) * 128 + (f2 & 31) * 4);
      float4 wv3 = *(const float4*)(wsrc + (f3 >> 5) * 128 + (f3 & 31) * 4);
      if (tid < 128) {
        AsT[nxt][sc4 + 0][sr] = av.x; AsT[nxt][sc4 + 1][sr] = av.y;
        AsT[nxt][sc4 + 2][sr] = av.z; AsT[nxt][sc4 + 3][sr] = av.w;
      }
      *(float4*)&Ws[nxt][f0 >> 5][(f0 & 31) * 4] = wv0;
      *(float4*)&Ws[nxt][f1 >> 5][(f1 & 31) * 4] = wv1;
      *(float4*)&Ws[nxt][f2 >> 5][(f2 & 31) * 4] = wv2;
      *(float4*)&Ws[nxt][f3 >> 5][(f3 & 31) * 4] = wv3;
    }
    #pragma unroll
    for (int kk = 0; kk < 32; ++kk) {
      float4 wv = *(float4*)&Ws[cur][kk][tx * 4];
      float2 av2 = *(float2*)&AsT[cur][kk][ty * 2];
      float aa[2] = {av2.x, av2.y};
      float ww[4] = {wv.x, wv.y, wv.z, wv.w};
      #pragma unroll
      for (int i = 0; i < 2; ++i)
        #pragma unroll
        for (int j = 0; j < 4; ++j)
          acc[i][j] = fmaf(aa[i], ww[j], acc[i][j]);
    }
    if (kc != 11) __syncthreads();
  }
  float4 bv = *(const float4*)(bias + tx * 4);
  float bb[4] = {bv.x, bv.y, bv.z, bv.w};
  #pragma unroll
  for (int i = 0; i < 2; ++i) {
    int r = ty * 2 + i;
    float4 o = make_float4(fmaxf(acc[i][0] + bb[0], 0.f),
                           fmaxf(acc[i][1] + bb[1], 0.f),
                           fmaxf(acc[i][2] + bb[2], 0.f),
                           fmaxf(acc[i][3] + bb[3], 0.f));
    *(float4*)(feat + (rowBase + r) * 128 + tx * 4) = o;
    *(float4*)(hn + (nodeBase + r) * 128 + tx * 4) = o;
  }
}

// ---------------- l2 norms over [H, L] per node ----------------------------
__global__ void k_l2(const float* __restrict__ h, const float* __restrict__ feat,
                     float* __restrict__ l2) {
  int wid = (blockIdx.x * 256 + threadIdx.x) >> 6;   // node id
  int lane = threadIdx.x & 63;
  int g = wid >> 10, local = wid & 1023;
  float s = 0.f;
  if (local >= INT_PG) {                              // leaf: 4*||h0||^2
    const float* p = h + wid * 128;
    float a = p[lane], b = p[lane + 64];
    s = (a * a + b * b) * 4.f;
  } else {
    int row = (g * INT_PG + local) * 128;
    #pragma unroll
    for (int l = 0; l < 4; ++l) {
      const float* p = feat + l * (M_INT * 128) + row;
      float a = p[lane], b = p[lane + 64];
      s += a * a + b * b;
    }
  }
  #pragma unroll
  for (int off = 32; off; off >>= 1) s += __shfl_down(s, off);
  if (lane == 0) l2[wid] = s;
}

// ------ fused top-8 + buildU: one block per graph --------------------------
__global__ __launch_bounds__(256) void k_topsel(const float* __restrict__ l2,
                                                const float* __restrict__ h,
                                                const float* __restrict__ feat,
                                                float* __restrict__ U,
                                                float* __restrict__ Vsum) {
  __shared__ int ssel[8];
  int g = blockIdx.x, tid = threadIdx.x;
  int lane = tid & 63;
  if (tid < 64) {
    unsigned long long kk[16];
    #pragma unroll
    for (int k = 0; k < 16; ++k) {
      int i = k * 64 + lane;
      unsigned vb = __float_as_uint(l2[g * 1024 + i]);  // l2 >= 0: uint order ok
      kk[k] = ((unsigned long long)vb << 32) | (unsigned)(~i);
    }
    for (int r = 0; r < 8; ++r) {
      unsigned long long best = 0ULL;
      #pragma unroll
      for (int k = 0; k < 16; ++k) best = (kk[k] > best) ? kk[k] : best;
      #pragma unroll
      for (int off = 32; off; off >>= 1) {
        unsigned long long o = __shfl_down(best, off);
        best = (o > best) ? o : best;
      }
      best = __shfl(best, 0);
      if (lane == 0) ssel[r] = (int)(~(unsigned)(best & 0xffffffffu));
      #pragma unroll
      for (int k = 0; k < 16; ++k) if (kk[k] == best) kk[k] = 0ULL;
    }
  }
  __syncthreads();
  for (int t = 0; t < 4; ++t) {
    int idx = t * 256 + tid;                  // 0..1023
    int rank = idx >> 7, hh = idx & 127;
    int local = ssel[rank];
    float4 v;
    if (local >= INT_PG) {
      float x = h[(g * NPG + local) * 128 + hh];
      v = make_float4(x, x, x, x);
    } else {
      int row = (g * INT_PG + local) * 128 + hh;
      v.x = feat[row];
      v.y = feat[M_INT * 128 + row];
      v.z = feat[2 * M_INT * 128 + row];
      v.w = feat[3 * M_INT * 128 + row];
    }
    int o = g * 1024 + rank * 128 + hh;
    ((float4*)U)[o] = v;
    ((float4*)Vsum)[o] = v;
  }
}

// ------------- VTS phase A: per-row softmax stats of alpha = U@Vsum.T ------
// R6: p = tid&15 (j-chunk of 64), r = tid>>4 (row rb+r). A row's 16 partials
// live in 16 adjacent lanes -> shfl_xor(8,4,2,1) reduce == old LDS-tree
// pairing (bit-identical). Vs staged chunk-transposed, stride-17 pad.
__global__ __launch_bounds__(1024) void k_vtsA(const float* __restrict__ U,
                                               const float* __restrict__ Vsum,
                                               float* __restrict__ mw, float* __restrict__ sw) {
  __shared__ float4 Vs2[64 * 17];   // 17.4 KB; elem j=p*64+i at [i*17+p]
  int g = blockIdx.x >> 4, rb = (blockIdx.x & 15) * 64;
  int tid = threadIdx.x, p = tid & 15, r = tid >> 4;
  Vs2[(tid & 63) * 17 + (tid >> 6)] = ((const float4*)Vsum)[g * 1024 + tid];
  __syncthreads();
  float4 u = ((const float4*)U)[g * 1024 + rb + r];
  float m = -3.4e38f;
  for (int i = 0; i < 64; ++i) {
    float4 v = Vs2[i * 17 + p];
    float a = u.x * v.x + u.y * v.y + u.z * v.z + u.w * v.w;
    m = fmaxf(m, a);
  }
  #pragma unroll
  for (int mk = 8; mk; mk >>= 1) m = fmaxf(m, __shfl_xor(m, mk));
  float s = 0.f;
  for (int i = 0; i < 64; ++i) {
    float4 v = Vs2[i * 17 + p];
    float a = u.x * v.x + u.y * v.y + u.z * v.z + u.w * v.w;
    s += __expf(a - m);
  }
  #pragma unroll
  for (int mk = 8; mk; mk >>= 1) s += __shfl_xor(s, mk);
  if (p == 0) {
    mw[g * 1024 + rb + r] = m;
    sw[g * 1024 + rb + r] = s;
  }
}

// ------------- VTS phase B: Vnew = beta.T @ U; update Vsum or emit SC ------
// R6: p = tid&15 (i-chunk of 64), q = tid>>4 (col cb+q); shfl_xor reduce
// (same pairing as old par tree -> bit-identical).
__global__ __launch_bounds__(1024) void k_vtsB(const float* __restrict__ U,
                                               float* __restrict__ Vsum,
                                               const float* __restrict__ mw,
                                               const float* __restrict__ sw,
                                               float* __restrict__ SCT, int last) {
  __shared__ float4 Us2[64 * 17];   // 17.4 KB; row i of chunk p at [i*17+p]
  __shared__ float2 Ms2[64 * 17];   // 8.7 KB  (m, 1/s)
  int g = blockIdx.x >> 4, cb = (blockIdx.x & 15) * 64;
  int tid = threadIdx.x, p = tid & 15, q = tid >> 4;
  Us2[(tid & 63) * 17 + (tid >> 6)] = ((const float4*)U)[g * 1024 + tid];
  Ms2[(tid & 63) * 17 + (tid >> 6)] =
      make_float2(mw[g * 1024 + tid], 1.0f / sw[g * 1024 + tid]);
  __syncthreads();
  float4 v = ((const float4*)Vsum)[g * 1024 + cb + q];
  float4 acc = make_float4(0.f, 0.f, 0.f, 0.f);
  for (int i = 0; i < 64; ++i) {
    float4 uu = Us2[i * 17 + p];
    float2 st = Ms2[i * 17 + p];
    float a = uu.x * v.x + uu.y * v.y + uu.z * v.z + uu.w * v.w;
    float w = __expf(a - st.x) * st.y;
    acc.x = fmaf(w, uu.x, acc.x); acc.y = fmaf(w, uu.y, acc.y);
    acc.z = fmaf(w, uu.z, acc.z); acc.w = fmaf(w, uu.w, acc.w);
  }
  #pragma unroll
  for (int mk = 8; mk; mk >>= 1) {
    acc.x += __shfl_xor(acc.x, mk);
    acc.y += __shfl_xor(acc.y, mk);
    acc.z += __shfl_xor(acc.z, mk);
    acc.w += __shfl_xor(acc.w, mk);
  }
  if (p == 0) {
    float4 o = acc;
    int jc = cb + q;
    if (last) {
      float sq = o.x * o.x + o.y * o.y + o.z * o.z + o.w * o.w;
      float f = (sq / (1.f + sq)) / (sqrtf(sq + 1e-10f) + 1e-8f);
      ((float4*)SCT)[jc * 32 + g] = make_float4(o.x * f, o.y * f, o.z * f, o.w * f);
    } else {
      float4 w0 = ((const float4*)Vsum)[g * 1024 + jc];
      ((float4*)Vsum)[g * 1024 + jc] = make_float4(w0.x + o.x, w0.y + o.y,
                                                   w0.z + o.z, w0.w + o.w);
    }
  }
}

// ---------------- Wjm[n][c][s][m] -> W_T[s][n][c][m] -----------------------
__global__ void k_transW(const float* __restrict__ Wjm, float* __restrict__ WT) {
  __shared__ float w[3200];
  int n = blockIdx.x, tid = threadIdx.x;
  for (int i = tid; i < 3200; i += 256) w[i] = Wjm[n * 3200 + i];
  __syncthreads();
  for (int i = tid; i < 3200; i += 256) {
    int s = i >> 6, cm = i & 63;
    int cc = cm >> 2, m = cm & 3;
    WT[(s * 1024 + n) * 64 + cm] = w[(cc * NS + s) * 4 + m];
  }
}

// ------------- Z sweep: accZ[b][s][c] += sum_n gamma * v -------------------
// R6: 32 n-chunks of 32 (grid 1600) -> 25 waves/CU (was 12.5).
__global__ __launch_bounds__(256) void k_zsweep(const float* __restrict__ WT,
                                                const float* __restrict__ SCT,
                                                const float* __restrict__ gT,
                                                float* __restrict__ accZ, int it0) {
  int sb = blockIdx.x >> 5, nb = blockIdx.x & 31;
  int tid = threadIdx.x;
  int b = tid & 31, ch = tid >> 5;             // ch in 0..7: c = ch, ch+8
  int n0 = nb * 32;
  const float4* wt = (const float4*)WT + (sb * 1024 + n0) * 16;
  const float4* sct = (const float4*)SCT + n0 * 32 + b;
  const float* gp = gT + (sb * 1024 + n0) * 32 + b;
  float a0 = 0.f, a1 = 0.f;
  #pragma unroll 4
  for (int nn = 0; nn < 32; ++nn) {
    float4 w0 = wt[nn * 16 + ch];
    float4 w1 = wt[nn * 16 + ch + 8];
    float4 s4 = sct[nn * 32];
    float gm = it0 ? (1.0f / 50.0f) : gp[nn * 32];
    float t0 = w0.x * s4.x + w0.y * s4.y + w0.z * s4.z + w0.w * s4.w;
    float t1 = w1.x * s4.x + w1.y * s4.y + w1.z * s4.z + w1.w * s4.w;
    a0 = fmaf(gm, t0, a0);
    a1 = fmaf(gm, t1, a1);
  }
  atomicAdd(accZ + (b * NS + sb) * 16 + ch, a0);
  atomicAdd(accZ + (b * NS + sb) * 16 + ch + 8, a1);
}

// ---------------- final logits from accZ (squash + norm) -------------------
__global__ void k_logits(const float* __restrict__ accZ, float* __restrict__ out) {
  int idx = blockIdx.x * 256 + threadIdx.x;
  if (idx >= 1600) return;
  const float4* a4 = (const float4*)accZ + idx * 4;
  float4 u0 = a4[0], u1 = a4[1], u2 = a4[2], u3 = a4[3];
  float sq = u0.x * u0.x + u0.y * u0.y + u0.z * u0.z + u0.w * u0.w
           + u1.x * u1.x + u1.y * u1.y + u1.z * u1.z + u1.w * u1.w
           + u2.x * u2.x + u2.y * u2.y + u2.z * u2.z + u2.w * u2.w
           + u3.x * u3.x + u3.y * u3.y + u3.z * u3.z + u3.w * u3.w;
  float f = (sq / (1.f + sq)) / (sqrtf(sq + 1e-10f) + 1e-8f);
  float lg = sqrtf(sq * f * f + 1e-10f);
  out[idx] = lg;
  out[idx + 1600] = lg;
}

// -- D sweep + gamma: dtot = delta_old + <v,z>; gT = softmax_s(dtot) --------
__global__ __launch_bounds__(256) void k_dsweep(const float* __restrict__ WT,
                                                const float* __restrict__ SCT,
                                                const float* __restrict__ accZ,
                                                float* __restrict__ delta,
                                                float* __restrict__ gT, int first) {
  __shared__ float wl[50 * 64];     // [s][c][m]  12.8 KB
  __shared__ float4 scl[32];        // SCT[n][b][:]
  __shared__ float dtot[NS][32];    // 6.4 KB
  __shared__ float mb[32], ib[32];
  int n = blockIdx.x;
  int tid = threadIdx.x;
  for (int i = tid; i < 3200; i += 256)
    wl[i] = WT[((i >> 6) * 1024 + n) * 64 + (i & 63)];
  if (tid < 32) scl[tid] = ((const float4*)SCT)[n * 32 + tid];
  __syncthreads();
  for (int idx = tid; idx < 1600; idx += 256) {
    int s = idx >> 5, b = idx & 31;              // lanes 0-31: same s (LDS bcast)
    const float4* wp = (const float4*)(wl + s * 64);
    const float4* zp = (const float4*)(accZ + (b * 50 + s) * 16);
    float4 u0 = zp[0], u1 = zp[1], u2 = zp[2], u3 = zp[3];
    float sq = u0.x * u0.x + u0.y * u0.y + u0.z * u0.z + u0.w * u0.w
             + u1.x * u1.x + u1.y * u1.y + u1.z * u1.z + u1.w * u1.w
             + u2.x * u2.x + u2.y * u2.y + u2.z * u2.z + u2.w * u2.w
             + u3.x * u3.x + u3.y * u3.y + u3.z * u3.z + u3.w * u3.w;
    float f = (sq / (1.f + sq)) / (sqrtf(sq + 1e-10f) + 1e-8f);
    float zs[16] = {u0.x * f, u0.y * f, u0.z * f, u0.w * f,
                    u1.x * f, u1.y * f, u1.z * f, u1.w * f,
                    u2.x * f, u2.y * f, u2.z * f, u2.w * f,
                    u3.x * f, u3.y * f, u3.z * f, u3.w * f};
    float4 y = make_float4(0.f, 0.f, 0.f, 0.f);
    #pragma unroll
    for (int c = 0; c < 16; ++c) {
      float4 w = wp[c];
      float zc = zs[c];
      y.x = fmaf(zc, w.x, y.x); y.y = fmaf(zc, w.y, y.y);
      y.z = fmaf(zc, w.z, y.z); y.w = fmaf(zc, w.w, y.w);
    }
    float4 sc = scl[b];
    float dd = sc.x * y.x + sc.y * y.y + sc.z * y.z + sc.w * y.w;
    float dt = first ? dd : (delta[(s * 1024 + n) * 32 + b] + dd);
    dtot[s][b] = dt;
    if (first) delta[(s * 1024 + n) * 32 + b] = dt;  // needed by next dsweep
  }
  __syncthreads();
  if (tid < 32) {                                    // softmax stats over s
    float m = -3.4e38f;
    for (int s = 0; s < NS; ++s) m = fmaxf(m, dtot[s][tid]);
    float sum = 0.f;
    for (int s = 0; s < NS; ++s) sum += __expf(dtot[s][tid] - m);
    mb[tid] = m; ib[tid] = 1.0f / sum;
  }
  __syncthreads();
  for (int idx = tid; idx < 1600; idx += 256) {
    int s = idx >> 5, b = idx & 31;
    gT[(s * 1024 + n) * 32 + b] = __expf(dtot[s][b] - mb[b]) * ib[b];
  }
}

// ---------------------------------------------------------------------------
extern "C" void kernel_launch(void* const* d_in, const int* in_sizes, int n_in,
                              void* d_out, int out_size, void* d_ws, size_t ws_size,
                              hipStream_t stream) {
  const int*   type_ids  = (const int*)d_in[0];
  const int*   token_ids = (const int*)d_in[1];
  const int*   src       = (const int*)d_in[2];
  const float* lw        = (const float*)d_in[4];
  const float* rw        = (const float*)d_in[5];
  const float* temb      = (const float*)d_in[7];
  const float* kemb      = (const float*)d_in[8];
  const float* Wl        = (const float*)d_in[9];
  const float* Wr        = (const float*)d_in[10];
  const float* Wt        = (const float*)d_in[11];
  const float* bconv     = (const float*)d_in[12];
  const float* Wjm       = (const float*)d_in[13];
  float* out = (float*)d_out;
  char* wsb = (char*)d_ws;

  // workspace layout (~79 MB used; ws is 256 MiB; no overlays)
  float* hA    = (float*)(wsb + 0);          // 16.78 MB (ping)
  float* hB    = (float*)(wsb + 16777216);   // 16.78 MB (pong)
  float* feat  = (float*)(wsb + 33554432);   // 16.78 MB
  float* WT    = (float*)(wsb + 50331648);   // 13.11 MB
  float* delta = (float*)(wsb + 63438848);   // 6.55  MB
  float* gT    = (float*)(wsb + 69992448);   // 6.55  MB
  float* accZ  = (float*)(wsb + 76546048);   // 3 x 100 KB (ping-pong)
  float* l2b   = (float*)(wsb + 76853248);   // 128 KB
  float* U     = (float*)(wsb + 76984320);   // 512 KB
  float* Vsum  = (float*)(wsb + 77508608);   // 512 KB
  float* mw    = (float*)(wsb + 78032896);   // 128 KB
  float* sw    = (float*)(wsb + 78163968);   // 128 KB
  float* SCT   = (float*)(wsb + 78295040);   // 512 KB

  k_embed<<<4096, 256, 0, stream>>>(type_ids, token_ids, temb, kemb, hA, hB);
  k_transW<<<1024, 256, 0, stream>>>(Wjm, WT);
  hipMemsetAsync(accZ, 0, 3 * 32 * 50 * 16 * 4, stream);   // all 3 iterations

  for (int l = 0; l < NLAY; ++l) {
    const float* hp = (l & 1) ? hB : hA;
    float*       hn = (l & 1) ? hA : hB;
    k_conv<<<512, 256, 0, stream>>>(hp, hn, src, lw, rw,
                                    Wl + l * 16384, Wr + l * 16384, Wt + l * 16384,
                                    bconv + l * 128, feat + l * (M_INT * 128));
  }

  // after 4 layers: internal nodes live in hA; leaves in hA since embed
  k_l2<<<8192, 256, 0, stream>>>(hA, feat, l2b);
  k_topsel<<<32, 256, 0, stream>>>(l2b, hA, feat, U, Vsum);

  for (int it = 0; it < 3; ++it) {
    k_vtsA<<<512, 1024, 0, stream>>>(U, Vsum, mw, sw);
    k_vtsB<<<512, 1024, 0, stream>>>(U, Vsum, mw, sw, SCT, it == 2 ? 1 : 0);
  }

  for (int it = 0; it < 3; ++it) {
    float* aZ = accZ + it * 25600;
    k_zsweep<<<1600, 256, 0, stream>>>(WT, SCT, gT, aZ, it == 0 ? 1 : 0);
    if (it < 2)
      k_dsweep<<<1024, 256, 0, stream>>>(WT, SCT, aZ, delta, gT, it == 0 ? 1 : 0);
  }
  k_logits<<<7, 256, 0, stream>>>(accZ + 2 * 25600, out);
}

// Round 5
// 431.960 us; speedup vs baseline: 1.1998x; 1.1998x over previous
//
#include <hip/hip_runtime.h>

// ---------------------------------------------------------------------------
// TreeCaps forward, MI355X fp32 implementation.
// Fixed forest: per graph of 1024 nodes, node p's children are 4p+1..4p+4;
// nodes 0..255 are internal (updated each layer), 256..1023 are leaves.
// R2: k_dsweep 1 block per node -> WT read exactly once.
// R3: conv fusion at 1 block/CU -> regression (staging serialized).
// R4: occupancy attack -> WIN (523->476).
// R5: conv gather-fusion retry + K-loop dbuf -> NEUTRAL (477); kept.
// R6: VTS shfl_xor rewrite (kept, ~neutral-to-positive) + zsweep grid 1600
//     -> REGRESSION (518): rocprof showed k_zsweep 60us x3, WRITE_SIZE
//     13.1 MB = 819200 atomics x 16B -> HBM-side RMWs are the bottleneck.
// R7: (this round) zsweep atomics ELIMINATED:
//   - stage 1 (grid 800 = 50 sb x 16 nb, 64 n each): partial sums to zpart
//     via plain coalesced stores (1.6 MB, L2-resident);
//   - stage 2 k_zred (100 blocks): deterministic 16-way sum -> accZ;
//   - accZ memset + ping-pong deleted (stage 2 overwrites fully).
// ---------------------------------------------------------------------------

#define BG      32
#define NPG     1024
#define HH      128
#define NLAY    4
#define INT_PG  256
#define M_INT   8192      // BG*INT_PG
#define NN      32768     // BG*NPG
#define EPG     1023
#define DCC     16
#define NS      50

// ------- embedding: h0 = concat(type_emb[t], token_emb[k]); leaves to both -
__global__ void k_embed(const int* __restrict__ tids, const int* __restrict__ kids,
                        const float* __restrict__ temb, const float* __restrict__ kemb,
                        float* __restrict__ hA, float* __restrict__ hB) {
  int idx = blockIdx.x * 256 + threadIdx.x;        // NN*32
  int n = idx >> 5, c4 = idx & 31;
  float4 v;
  if (c4 < 16) v = *(const float4*)(temb + tids[n] * 64 + c4 * 4);
  else         v = *(const float4*)(kemb + kids[n] * 64 + (c4 - 16) * 4);
  *(float4*)(hA + n * 128 + c4 * 4) = v;
  if ((n & 1023) >= INT_PG)                        // leaves constant in both bufs
    *(float4*)(hB + n * 128 + c4 * 4) = v;
}

// --- fused gather+conv: new_h = relu(hl@Wl + hr@Wr + h@Wt + b) -------------
// [8192 rows, K=384, N=128]; block = 256 thr, 16 rows x 128 cols, 2x4/thread.
// 512 blocks (2/CU). Children of the block's 16 parents = contiguous local
// slice staged to LDS with k_gather's exact fma order. K-loop double-buffered.
__global__ __launch_bounds__(256) void k_conv(
    const float* __restrict__ hp, float* __restrict__ hn,
    const int* __restrict__ src, const float* __restrict__ lw,
    const float* __restrict__ rw,
    const float* __restrict__ Wl, const float* __restrict__ Wr,
    const float* __restrict__ Wt, const float* __restrict__ bias,
    float* __restrict__ feat) {
  __shared__ float Ws[2][32][128];   // 32 KB
  __shared__ float AsT[2][32][20];   // 5 KB, padded
  __shared__ float hlS[16][128];     // 8 KB
  __shared__ float hrS[16][128];     // 8 KB
  int tid = threadIdx.x;
  int tx = tid & 31, ty = tid >> 5;          // ty 0..7 -> rows 2*ty, 2*ty+1
  int rowBase = blockIdx.x * 16;
  int g = rowBase >> 8, plBase = rowBase & 255;
  int nodeBase = g * NPG + plBase;

  // ---- stage weighted child sums for 16 parents (k_gather fma order) ----
  #pragma unroll
  for (int t = 0; t < 2; ++t) {
    int it = t * 256 + tid;                  // 0..511
    int pw = it >> 5, c4 = it & 31;
    int pl = plBase + pw;
    float4 al = make_float4(0.f, 0.f, 0.f, 0.f);
    float4 ar = make_float4(0.f, 0.f, 0.f, 0.f);
    #pragma unroll
    for (int j = 0; j < 4; ++j) {
      int cc = 4 * pl + 1 + j;
      if (cc < NPG) {
        int e = g * EPG + cc - 1;
        int child = src[e];
        float lv = lw[e], rv = rw[e];
        float4 hv = *(const float4*)(hp + child * 128 + c4 * 4);
        al.x = fmaf(lv, hv.x, al.x); al.y = fmaf(lv, hv.y, al.y);
        al.z = fmaf(lv, hv.z, al.z); al.w = fmaf(lv, hv.w, al.w);
        ar.x = fmaf(rv, hv.x, ar.x); ar.y = fmaf(rv, hv.y, ar.y);
        ar.z = fmaf(rv, hv.z, ar.z); ar.w = fmaf(rv, hv.w, ar.w);
      }
    }
    *(float4*)&hlS[pw][c4 * 4] = al;
    *(float4*)&hrS[pw][c4 * 4] = ar;
  }
  __syncthreads();

  float acc[2][4] = {};
  int sr = tid >> 3, sc4 = (tid & 7) * 4;    // valid for tid<128: sr 0..15

  // prologue: load kc=0 into buffer 0 (ssel=0 -> hlS)
  {
    float4 av = make_float4(0.f, 0.f, 0.f, 0.f);
    if (tid < 128) av = *(const float4*)&hlS[sr][sc4];
    const float* wsrc = Wl;                  // kcol = 0
    int f0 = tid, f1 = tid + 256, f2 = tid + 512, f3 = tid + 768;
    float4 wv0 = *(const float4*)(wsrc + (f0 >> 5) * 128 + (f0 & 31) * 4);
    float4 wv1 = *(const float4*)(wsrc + (f1 >> 5) * 128 + (f1 & 31) * 4);
    float4 wv2 = *(const float4*)(wsrc + (f2 >> 5) * 128 + (f2 & 31) * 4);
    float4 wv3 = *(const float4*)(wsrc + (f3 >> 5) * 128 + (f3 & 31) * 4);
    if (tid < 128) {
      AsT[0][sc4 + 0][sr] = av.x; AsT[0][sc4 + 1][sr] = av.y;
      AsT[0][sc4 + 2][sr] = av.z; AsT[0][sc4 + 3][sr] = av.w;
    }
    *(float4*)&Ws[0][f0 >> 5][(f0 & 31) * 4] = wv0;
    *(float4*)&Ws[0][f1 >> 5][(f1 & 31) * 4] = wv1;
    *(float4*)&Ws[0][f2 >> 5][(f2 & 31) * 4] = wv2;
    *(float4*)&Ws[0][f3 >> 5][(f3 & 31) * 4] = wv3;
  }
  __syncthreads();

  for (int kc = 0; kc < 12; ++kc) {
    int cur = kc & 1, nxt = cur ^ 1;
    if (kc < 11) {                           // prefetch kc+1 into nxt
      int kc1 = kc + 1;
      int ssel = kc1 >> 2, kcol = (kc1 & 3) * 32;
      float4 av = make_float4(0.f, 0.f, 0.f, 0.f);
      if (tid < 128) {
        if (ssel == 0)      av = *(const float4*)&hlS[sr][kcol + sc4];
        else if (ssel == 1) av = *(const float4*)&hrS[sr][kcol + sc4];
        else                av = *(const float4*)(hp + (nodeBase + sr) * 128 + kcol + sc4);
      }
      const float* wsrc = ((ssel == 0) ? Wl : (ssel == 1) ? Wr : Wt) + kcol * 128;
      int f0 = tid, f1 = tid + 256, f2 = tid + 512, f3 = tid + 768;
      float4 wv0 = *(const float4*)(wsrc + (f0 >> 5) * 128 + (f0 & 31) * 4);
      float4 wv1 = *(const float4*)(wsrc + (f1 >> 5) * 128 + (f1 & 31) * 4);
      float4 wv2 = *(const float4*)(wsrc + (f2 >> 5) * 128 + (f2 & 31) * 4);
      float4 wv3 = *(const float4*)(wsrc + (f3 >> 5) * 128 + (f3 & 31) * 4);
      if (tid < 128) {
        AsT[nxt][sc4 + 0][sr] = av.x; AsT[nxt][sc4 + 1][sr] = av.y;
        AsT[nxt][sc4 + 2][sr] = av.z; AsT[nxt][sc4 + 3][sr] = av.w;
      }
      *(float4*)&Ws[nxt][f0 >> 5][(f0 & 31) * 4] = wv0;
      *(float4*)&Ws[nxt][f1 >> 5][(f1 & 31) * 4] = wv1;
      *(float4*)&Ws[nxt][f2 >> 5][(f2 & 31) * 4] = wv2;
      *(float4*)&Ws[nxt][f3 >> 5][(f3 & 31) * 4] = wv3;
    }
    #pragma unroll
    for (int kk = 0; kk < 32; ++kk) {
      float4 wv = *(float4*)&Ws[cur][kk][tx * 4];
      float2 av2 = *(float2*)&AsT[cur][kk][ty * 2];
      float aa[2] = {av2.x, av2.y};
      float ww[4] = {wv.x, wv.y, wv.z, wv.w};
      #pragma unroll
      for (int i = 0; i < 2; ++i)
        #pragma unroll
        for (int j = 0; j < 4; ++j)
          acc[i][j] = fmaf(aa[i], ww[j], acc[i][j]);
    }
    if (kc != 11) __syncthreads();
  }
  float4 bv = *(const float4*)(bias + tx * 4);
  float bb[4] = {bv.x, bv.y, bv.z, bv.w};
  #pragma unroll
  for (int i = 0; i < 2; ++i) {
    int r = ty * 2 + i;
    float4 o = make_float4(fmaxf(acc[i][0] + bb[0], 0.f),
                           fmaxf(acc[i][1] + bb[1], 0.f),
                           fmaxf(acc[i][2] + bb[2], 0.f),
                           fmaxf(acc[i][3] + bb[3], 0.f));
    *(float4*)(feat + (rowBase + r) * 128 + tx * 4) = o;
    *(float4*)(hn + (nodeBase + r) * 128 + tx * 4) = o;
  }
}

// ---------------- l2 norms over [H, L] per node ----------------------------
__global__ void k_l2(const float* __restrict__ h, const float* __restrict__ feat,
                     float* __restrict__ l2) {
  int wid = (blockIdx.x * 256 + threadIdx.x) >> 6;   // node id
  int lane = threadIdx.x & 63;
  int g = wid >> 10, local = wid & 1023;
  float s = 0.f;
  if (local >= INT_PG) {                              // leaf: 4*||h0||^2
    const float* p = h + wid * 128;
    float a = p[lane], b = p[lane + 64];
    s = (a * a + b * b) * 4.f;
  } else {
    int row = (g * INT_PG + local) * 128;
    #pragma unroll
    for (int l = 0; l < 4; ++l) {
      const float* p = feat + l * (M_INT * 128) + row;
      float a = p[lane], b = p[lane + 64];
      s += a * a + b * b;
    }
  }
  #pragma unroll
  for (int off = 32; off; off >>= 1) s += __shfl_down(s, off);
  if (lane == 0) l2[wid] = s;
}

// ------ fused top-8 + buildU: one block per graph --------------------------
__global__ __launch_bounds__(256) void k_topsel(const float* __restrict__ l2,
                                                const float* __restrict__ h,
                                                const float* __restrict__ feat,
                                                float* __restrict__ U,
                                                float* __restrict__ Vsum) {
  __shared__ int ssel[8];
  int g = blockIdx.x, tid = threadIdx.x;
  int lane = tid & 63;
  if (tid < 64) {
    unsigned long long kk[16];
    #pragma unroll
    for (int k = 0; k < 16; ++k) {
      int i = k * 64 + lane;
      unsigned vb = __float_as_uint(l2[g * 1024 + i]);  // l2 >= 0: uint order ok
      kk[k] = ((unsigned long long)vb << 32) | (unsigned)(~i);
    }
    for (int r = 0; r < 8; ++r) {
      unsigned long long best = 0ULL;
      #pragma unroll
      for (int k = 0; k < 16; ++k) best = (kk[k] > best) ? kk[k] : best;
      #pragma unroll
      for (int off = 32; off; off >>= 1) {
        unsigned long long o = __shfl_down(best, off);
        best = (o > best) ? o : best;
      }
      best = __shfl(best, 0);
      if (lane == 0) ssel[r] = (int)(~(unsigned)(best & 0xffffffffu));
      #pragma unroll
      for (int k = 0; k < 16; ++k) if (kk[k] == best) kk[k] = 0ULL;
    }
  }
  __syncthreads();
  for (int t = 0; t < 4; ++t) {
    int idx = t * 256 + tid;                  // 0..1023
    int rank = idx >> 7, hh = idx & 127;
    int local = ssel[rank];
    float4 v;
    if (local >= INT_PG) {
      float x = h[(g * NPG + local) * 128 + hh];
      v = make_float4(x, x, x, x);
    } else {
      int row = (g * INT_PG + local) * 128 + hh;
      v.x = feat[row];
      v.y = feat[M_INT * 128 + row];
      v.z = feat[2 * M_INT * 128 + row];
      v.w = feat[3 * M_INT * 128 + row];
    }
    int o = g * 1024 + rank * 128 + hh;
    ((float4*)U)[o] = v;
    ((float4*)Vsum)[o] = v;
  }
}

// ------------- VTS phase A: per-row softmax stats of alpha = U@Vsum.T ------
// p = tid&15 (j-chunk of 64), r = tid>>4 (row rb+r); shfl_xor(8,4,2,1)
// reduce == old LDS-tree pairing (bit-identical).
__global__ __launch_bounds__(1024) void k_vtsA(const float* __restrict__ U,
                                               const float* __restrict__ Vsum,
                                               float* __restrict__ mw, float* __restrict__ sw) {
  __shared__ float4 Vs2[64 * 17];   // 17.4 KB; elem j=p*64+i at [i*17+p]
  int g = blockIdx.x >> 4, rb = (blockIdx.x & 15) * 64;
  int tid = threadIdx.x, p = tid & 15, r = tid >> 4;
  Vs2[(tid & 63) * 17 + (tid >> 6)] = ((const float4*)Vsum)[g * 1024 + tid];
  __syncthreads();
  float4 u = ((const float4*)U)[g * 1024 + rb + r];
  float m = -3.4e38f;
  for (int i = 0; i < 64; ++i) {
    float4 v = Vs2[i * 17 + p];
    float a = u.x * v.x + u.y * v.y + u.z * v.z + u.w * v.w;
    m = fmaxf(m, a);
  }
  #pragma unroll
  for (int mk = 8; mk; mk >>= 1) m = fmaxf(m, __shfl_xor(m, mk));
  float s = 0.f;
  for (int i = 0; i < 64; ++i) {
    float4 v = Vs2[i * 17 + p];
    float a = u.x * v.x + u.y * v.y + u.z * v.z + u.w * v.w;
    s += __expf(a - m);
  }
  #pragma unroll
  for (int mk = 8; mk; mk >>= 1) s += __shfl_xor(s, mk);
  if (p == 0) {
    mw[g * 1024 + rb + r] = m;
    sw[g * 1024 + rb + r] = s;
  }
}

// ------------- VTS phase B: Vnew = beta.T @ U; update Vsum or emit SC ------
__global__ __launch_bounds__(1024) void k_vtsB(const float* __restrict__ U,
                                               float* __restrict__ Vsum,
                                               const float* __restrict__ mw,
                                               const float* __restrict__ sw,
                                               float* __restrict__ SCT, int last) {
  __shared__ float4 Us2[64 * 17];   // 17.4 KB; row i of chunk p at [i*17+p]
  __shared__ float2 Ms2[64 * 17];   // 8.7 KB  (m, 1/s)
  int g = blockIdx.x >> 4, cb = (blockIdx.x & 15) * 64;
  int tid = threadIdx.x, p = tid & 15, q = tid >> 4;
  Us2[(tid & 63) * 17 + (tid >> 6)] = ((const float4*)U)[g * 1024 + tid];
  Ms2[(tid & 63) * 17 + (tid >> 6)] =
      make_float2(mw[g * 1024 + tid], 1.0f / sw[g * 1024 + tid]);
  __syncthreads();
  float4 v = ((const float4*)Vsum)[g * 1024 + cb + q];
  float4 acc = make_float4(0.f, 0.f, 0.f, 0.f);
  for (int i = 0; i < 64; ++i) {
    float4 uu = Us2[i * 17 + p];
    float2 st = Ms2[i * 17 + p];
    float a = uu.x * v.x + uu.y * v.y + uu.z * v.z + uu.w * v.w;
    float w = __expf(a - st.x) * st.y;
    acc.x = fmaf(w, uu.x, acc.x); acc.y = fmaf(w, uu.y, acc.y);
    acc.z = fmaf(w, uu.z, acc.z); acc.w = fmaf(w, uu.w, acc.w);
  }
  #pragma unroll
  for (int mk = 8; mk; mk >>= 1) {
    acc.x += __shfl_xor(acc.x, mk);
    acc.y += __shfl_xor(acc.y, mk);
    acc.z += __shfl_xor(acc.z, mk);
    acc.w += __shfl_xor(acc.w, mk);
  }
  if (p == 0) {
    float4 o = acc;
    int jc = cb + q;
    if (last) {
      float sq = o.x * o.x + o.y * o.y + o.z * o.z + o.w * o.w;
      float f = (sq / (1.f + sq)) / (sqrtf(sq + 1e-10f) + 1e-8f);
      ((float4*)SCT)[jc * 32 + g] = make_float4(o.x * f, o.y * f, o.z * f, o.w * f);
    } else {
      float4 w0 = ((const float4*)Vsum)[g * 1024 + jc];
      ((float4*)Vsum)[g * 1024 + jc] = make_float4(w0.x + o.x, w0.y + o.y,
                                                   w0.z + o.z, w0.w + o.w);
    }
  }
}

// ---------------- Wjm[n][c][s][m] -> W_T[s][n][c][m] -----------------------
__global__ void k_transW(const float* __restrict__ Wjm, float* __restrict__ WT) {
  __shared__ float w[3200];
  int n = blockIdx.x, tid = threadIdx.x;
  for (int i = tid; i < 3200; i += 256) w[i] = Wjm[n * 3200 + i];
  __syncthreads();
  for (int i = tid; i < 3200; i += 256) {
    int s = i >> 6, cm = i & 63;
    int cc = cm >> 2, m = cm & 3;
    WT[(s * 1024 + n) * 64 + cm] = w[(cc * NS + s) * 4 + m];
  }
}

// ------------- Z sweep stage 1: partial sums, NO atomics -------------------
// R7: grid 800 = 50 sb x 16 nb, 64 n each. Block writes 512 partials with
// plain coalesced stores (zpart L2-resident, 1.6 MB total).
__global__ __launch_bounds__(256) void k_zsweep(const float* __restrict__ WT,
                                                const float* __restrict__ SCT,
                                                const float* __restrict__ gT,
                                                float* __restrict__ zpart, int it0) {
  int sb = blockIdx.x >> 4, nb = blockIdx.x & 15;
  int tid = threadIdx.x;
  int b = tid & 31, ch = tid >> 5;             // ch in 0..7: c = ch, ch+8
  int n0 = nb * 64;
  const float4* wt = (const float4*)WT + (sb * 1024 + n0) * 16;
  const float4* sct = (const float4*)SCT + n0 * 32 + b;
  const float* gp = gT + (sb * 1024 + n0) * 32 + b;
  float a0 = 0.f, a1 = 0.f;
  #pragma unroll 8
  for (int nn = 0; nn < 64; ++nn) {
    float4 w0 = wt[nn * 16 + ch];
    float4 w1 = wt[nn * 16 + ch + 8];
    float4 s4 = sct[nn * 32];
    float gm = it0 ? (1.0f / 50.0f) : gp[nn * 32];
    float t0 = w0.x * s4.x + w0.y * s4.y + w0.z * s4.z + w0.w * s4.w;
    float t1 = w1.x * s4.x + w1.y * s4.y + w1.z * s4.z + w1.w * s4.w;
    a0 = fmaf(gm, t0, a0);
    a1 = fmaf(gm, t1, a1);
  }
  // layout: zpart[blk][tid] = a0 (c=ch), zpart[blk][256+tid] = a1 (c=ch+8)
  zpart[blockIdx.x * 512 + tid] = a0;
  zpart[blockIdx.x * 512 + 256 + tid] = a1;
}

// ------------- Z sweep stage 2: accZ[b][s][c] = sum_nb partials ------------
__global__ void k_zred(const float* __restrict__ zpart, float* __restrict__ accZ) {
  int idx = blockIdx.x * 256 + threadIdx.x;    // 25600 = (b*NS+sb)*16+c
  if (idx >= 25600) return;
  int c = idx & 15;
  int sb = (idx >> 4) % NS;
  int b = idx / (16 * NS);
  int lofs = (c < 8) ? (c * 32 + b) : (256 + (c - 8) * 32 + b);
  const float* zp = zpart + sb * 16 * 512 + lofs;
  float s = 0.f;
  #pragma unroll
  for (int nb = 0; nb < 16; ++nb) s += zp[nb * 512];
  accZ[idx] = s;
}

// ---------------- final logits from accZ (squash + norm) -------------------
__global__ void k_logits(const float* __restrict__ accZ, float* __restrict__ out) {
  int idx = blockIdx.x * 256 + threadIdx.x;
  if (idx >= 1600) return;
  const float4* a4 = (const float4*)accZ + idx * 4;
  float4 u0 = a4[0], u1 = a4[1], u2 = a4[2], u3 = a4[3];
  float sq = u0.x * u0.x + u0.y * u0.y + u0.z * u0.z + u0.w * u0.w
           + u1.x * u1.x + u1.y * u1.y + u1.z * u1.z + u1.w * u1.w
           + u2.x * u2.x + u2.y * u2.y + u2.z * u2.z + u2.w * u2.w
           + u3.x * u3.x + u3.y * u3.y + u3.z * u3.z + u3.w * u3.w;
  float f = (sq / (1.f + sq)) / (sqrtf(sq + 1e-10f) + 1e-8f);
  float lg = sqrtf(sq * f * f + 1e-10f);
  out[idx] = lg;
  out[idx + 1600] = lg;
}

// -- D sweep + gamma: dtot = delta_old + <v,z>; gT = softmax_s(dtot) --------
__global__ __launch_bounds__(256) void k_dsweep(const float* __restrict__ WT,
                                                const float* __restrict__ SCT,
                                                const float* __restrict__ accZ,
                                                float* __restrict__ delta,
                                                float* __restrict__ gT, int first) {
  __shared__ float wl[50 * 64];     // [s][c][m]  12.8 KB
  __shared__ float4 scl[32];        // SCT[n][b][:]
  __shared__ float dtot[NS][32];    // 6.4 KB
  __shared__ float mb[32], ib[32];
  int n = blockIdx.x;
  int tid = threadIdx.x;
  for (int i = tid; i < 3200; i += 256)
    wl[i] = WT[((i >> 6) * 1024 + n) * 64 + (i & 63)];
  if (tid < 32) scl[tid] = ((const float4*)SCT)[n * 32 + tid];
  __syncthreads();
  for (int idx = tid; idx < 1600; idx += 256) {
    int s = idx >> 5, b = idx & 31;              // lanes 0-31: same s (LDS bcast)
    const float4* wp = (const float4*)(wl + s * 64);
    const float4* zp = (const float4*)(accZ + (b * 50 + s) * 16);
    float4 u0 = zp[0], u1 = zp[1], u2 = zp[2], u3 = zp[3];
    float sq = u0.x * u0.x + u0.y * u0.y + u0.z * u0.z + u0.w * u0.w
             + u1.x * u1.x + u1.y * u1.y + u1.z * u1.z + u1.w * u1.w
             + u2.x * u2.x + u2.y * u2.y + u2.z * u2.z + u2.w * u2.w
             + u3.x * u3.x + u3.y * u3.y + u3.z * u3.z + u3.w * u3.w;
    float f = (sq / (1.f + sq)) / (sqrtf(sq + 1e-10f) + 1e-8f);
    float zs[16] = {u0.x * f, u0.y * f, u0.z * f, u0.w * f,
                    u1.x * f, u1.y * f, u1.z * f, u1.w * f,
                    u2.x * f, u2.y * f, u2.z * f, u2.w * f,
                    u3.x * f, u3.y * f, u3.z * f, u3.w * f};
    float4 y = make_float4(0.f, 0.f, 0.f, 0.f);
    #pragma unroll
    for (int c = 0; c < 16; ++c) {
      float4 w = wp[c];
      float zc = zs[c];
      y.x = fmaf(zc, w.x, y.x); y.y = fmaf(zc, w.y, y.y);
      y.z = fmaf(zc, w.z, y.z); y.w = fmaf(zc, w.w, y.w);
    }
    float4 sc = scl[b];
    float dd = sc.x * y.x + sc.y * y.y + sc.z * y.z + sc.w * y.w;
    float dt = first ? dd : (delta[(s * 1024 + n) * 32 + b] + dd);
    dtot[s][b] = dt;
    if (first) delta[(s * 1024 + n) * 32 + b] = dt;  // needed by next dsweep
  }
  __syncthreads();
  if (tid < 32) {                                    // softmax stats over s
    float m = -3.4e38f;
    for (int s = 0; s < NS; ++s) m = fmaxf(m, dtot[s][tid]);
    float sum = 0.f;
    for (int s = 0; s < NS; ++s) sum += __expf(dtot[s][tid] - m);
    mb[tid] = m; ib[tid] = 1.0f / sum;
  }
  __syncthreads();
  for (int idx = tid; idx < 1600; idx += 256) {
    int s = idx >> 5, b = idx & 31;
    gT[(s * 1024 + n) * 32 + b] = __expf(dtot[s][b] - mb[b]) * ib[b];
  }
}

// ---------------------------------------------------------------------------
extern "C" void kernel_launch(void* const* d_in, const int* in_sizes, int n_in,
                              void* d_out, int out_size, void* d_ws, size_t ws_size,
                              hipStream_t stream) {
  const int*   type_ids  = (const int*)d_in[0];
  const int*   token_ids = (const int*)d_in[1];
  const int*   src       = (const int*)d_in[2];
  const float* lw        = (const float*)d_in[4];
  const float* rw        = (const float*)d_in[5];
  const float* temb      = (const float*)d_in[7];
  const float* kemb      = (const float*)d_in[8];
  const float* Wl        = (const float*)d_in[9];
  const float* Wr        = (const float*)d_in[10];
  const float* Wt        = (const float*)d_in[11];
  const float* bconv     = (const float*)d_in[12];
  const float* Wjm       = (const float*)d_in[13];
  float* out = (float*)d_out;
  char* wsb = (char*)d_ws;

  // workspace layout (~81 MB used; ws is 256 MiB; no overlays)
  float* hA    = (float*)(wsb + 0);          // 16.78 MB (ping)
  float* hB    = (float*)(wsb + 16777216);   // 16.78 MB (pong)
  float* feat  = (float*)(wsb + 33554432);   // 16.78 MB
  float* WT    = (float*)(wsb + 50331648);   // 13.11 MB
  float* delta = (float*)(wsb + 63438848);   // 6.55  MB
  float* gT    = (float*)(wsb + 69992448);   // 6.55  MB
  float* accZ  = (float*)(wsb + 76546048);   // 100 KB
  float* l2b   = (float*)(wsb + 76853248);   // 128 KB
  float* U     = (float*)(wsb + 76984320);   // 512 KB
  float* Vsum  = (float*)(wsb + 77508608);   // 512 KB
  float* mw    = (float*)(wsb + 78032896);   // 128 KB
  float* sw    = (float*)(wsb + 78163968);   // 128 KB
  float* SCT   = (float*)(wsb + 78295040);   // 512 KB
  float* zpart = (float*)(wsb + 78819328);   // 1.64 MB (800 x 512)

  k_embed<<<4096, 256, 0, stream>>>(type_ids, token_ids, temb, kemb, hA, hB);
  k_transW<<<1024, 256, 0, stream>>>(Wjm, WT);

  for (int l = 0; l < NLAY; ++l) {
    const float* hp = (l & 1) ? hB : hA;
    float*       hn = (l & 1) ? hA : hB;
    k_conv<<<512, 256, 0, stream>>>(hp, hn, src, lw, rw,
                                    Wl + l * 16384, Wr + l * 16384, Wt + l * 16384,
                                    bconv + l * 128, feat + l * (M_INT * 128));
  }

  // after 4 layers: internal nodes live in hA; leaves in hA since embed
  k_l2<<<8192, 256, 0, stream>>>(hA, feat, l2b);
  k_topsel<<<32, 256, 0, stream>>>(l2b, hA, feat, U, Vsum);

  for (int it = 0; it < 3; ++it) {
    k_vtsA<<<512, 1024, 0, stream>>>(U, Vsum, mw, sw);
    k_vtsB<<<512, 1024, 0, stream>>>(U, Vsum, mw, sw, SCT, it == 2 ? 1 : 0);
  }

  for (int it = 0; it < 3; ++it) {
    k_zsweep<<<800, 256, 0, stream>>>(WT, SCT, gT, zpart, it == 0 ? 1 : 0);
    k_zred<<<100, 256, 0, stream>>>(zpart, accZ);
    if (it < 2)
      k_dsweep<<<1024, 256, 0, stream>>>(WT, SCT, accZ, delta, gT, it == 0 ? 1 : 0);
  }
  k_logits<<<7, 256, 0, stream>>>(accZ, out);
}